// Round 1
// baseline (540.941 us; speedup 1.0000x reference)
//
#include <hip/hip_runtime.h>
#include <hip/hip_bf16.h>

// Problem constants (fixed by the reference): B=8, L=256, D=128, H=4, HD=32
constexpr int Bc = 8;
constexpr int Lc = 256;
constexpr int Dc = 128;
constexpr int Hc = 4;
constexpr int HDc = 32;

// ---------------------------------------------------------------------------
// Kernel 1: fused projections
//   qout = queries @ Wq + bq
//   ksum = keys    @ Wk + bk + abs_pos_K
//   vsum = keys    @ Wv + bv + abs_pos_V
// One block = 8 rows x 128 cols of all three outputs. 256 blocks total.
// A-tiles staged in LDS (broadcast reads); W columns from L2.
// ---------------------------------------------------------------------------
__global__ __launch_bounds__(256)
void proj_kernel(const float* __restrict__ queries, const float* __restrict__ keys,
                 const float* __restrict__ pk, const float* __restrict__ pv,
                 const float* __restrict__ Wq, const float* __restrict__ bq,
                 const float* __restrict__ Wk, const float* __restrict__ bk,
                 const float* __restrict__ Wv, const float* __restrict__ bv,
                 float* __restrict__ qout, float* __restrict__ ksum,
                 float* __restrict__ vsum)
{
    __shared__ float Aq[8][132];   // +4 pad: conflict-free, float4-aligned (528 B rows)
    __shared__ float Ak[8][132];
    const int t = threadIdx.x;
    const int row0 = blockIdx.x * 8;

    // Stage 8x128 A-tiles, coalesced float4 loads (one float4 per thread)
    {
        const int r = t >> 5;
        const int c4 = (t & 31) * 4;
        const float4 qv = *(const float4*)&queries[(size_t)(row0 + r) * Dc + c4];
        const float4 kv = *(const float4*)&keys[(size_t)(row0 + r) * Dc + c4];
        *(float4*)&Aq[r][c4] = qv;
        *(float4*)&Ak[r][c4] = kv;
    }
    __syncthreads();

    const int col = t & 127;
    const int rg  = t >> 7;      // 0..1 -> rows rg*4 .. rg*4+3
    float fq[4] = {0.f, 0.f, 0.f, 0.f};
    float fk[4] = {0.f, 0.f, 0.f, 0.f};
    float fv[4] = {0.f, 0.f, 0.f, 0.f};

    for (int k = 0; k < Dc; k += 4) {
        float4 a[4], c[4];
        #pragma unroll
        for (int r = 0; r < 4; ++r) {
            a[r] = *(const float4*)&Aq[rg * 4 + r][k];   // LDS broadcast (uniform addr/wave)
            c[r] = *(const float4*)&Ak[rg * 4 + r][k];
        }
        #pragma unroll
        for (int kk = 0; kk < 4; ++kk) {
            const float wq = Wq[(size_t)(k + kk) * Dc + col];
            const float wk = Wk[(size_t)(k + kk) * Dc + col];
            const float wv = Wv[(size_t)(k + kk) * Dc + col];
            #pragma unroll
            for (int r = 0; r < 4; ++r) {
                const float av = (&a[r].x)[kk];
                const float cv = (&c[r].x)[kk];
                fq[r] = fmaf(av, wq, fq[r]);
                fk[r] = fmaf(cv, wk, fk[r]);
                fv[r] = fmaf(cv, wv, fv[r]);
            }
        }
    }

    const float bqv = bq[col], bkv = bk[col], bvv = bv[col];
    #pragma unroll
    for (int r = 0; r < 4; ++r) {
        const int row = row0 + rg * 4 + r;
        const size_t idx = (size_t)row * Dc + col;
        qout[idx] = fq[r] + bqv;
        ksum[idx] = fk[r] + bkv + pk[idx];
        vsum[idx] = fv[r] + bvv + pv[idx];
    }
}

// ---------------------------------------------------------------------------
// Kernel 2: fused time-aware attention, one block per (b, l) query row.
//   scores[h][m] = q[b,l,h,:] . (ksum[b,m,h,:] + tK[b,l,m,h,:]) * 1/sqrt(32)
//   causal: only m <= l; padded rows: all-NEG -> exactly uniform 1/256 weights
//   out[b,l,:] = sum_m w[h(m?),m] * (vsum[b,m,:] + tV[b,l,m,:])
// Traffic savings: padded rows skip tK entirely; non-padded rows read only
// m <= l of both tK and tV slabs.
// ---------------------------------------------------------------------------
__global__ __launch_bounds__(256)
void attn_kernel(const float* __restrict__ qproj, const float* __restrict__ ksum,
                 const float* __restrict__ vsum, const float* __restrict__ tK,
                 const float* __restrict__ tV,
                 const unsigned char* __restrict__ pmask,
                 const unsigned char* __restrict__ amask,
                 float* __restrict__ out)
{
    __shared__ float  sS[Hc][Lc + 8];   // stride 264: (264%32)=8 -> <=2-way on score store
    __shared__ float  wT[Lc][Hc];       // weights, transposed for phase-B reads
    __shared__ float4 pAcc[8][32];      // phase-B partials

    const int t = threadIdx.x;
    const int bid = blockIdx.x;
    const int b = bid >> 8;
    const int l = bid & 255;

    // Runtime bool-encoding detection: attn_mask[0][1] is True by construction.
    // byte[1] == 1  -> bools are 1-byte; byte[1] == 0 -> bools widened to int32.
    const int pmStride = (amask[1] != 0) ? 1 : 4;
    const bool padded = pmask[(size_t)(b * Lc + l) * pmStride] != 0;

    const float scale = 0.17677669529663687f;  // 1/sqrt(HD)

    if (!padded) {
        // ---- Phase A: scores. thread t -> head h = t&3, m = (t>>2) + j*64 ----
        const int h  = t & 3;
        const int m0 = t >> 2;
        const float4* q4 = (const float4*)(qproj + ((size_t)(b * Lc + l)) * Dc + h * HDc);
        float4 qr[8];
        #pragma unroll
        for (int i = 0; i < 8; ++i) qr[i] = q4[i];

        const float* tKbase = tK + ((size_t)(b * Lc + l)) * Lc * Dc;
        #pragma unroll
        for (int j = 0; j < 4; ++j) {
            const int m = m0 + j * 64;
            float sc = -3.0e38f;               // masked (future) positions
            if (m <= l) {
                const float4* kt4 = (const float4*)(tKbase + (size_t)m * Dc + h * HDc);
                const float4* ks4 = (const float4*)(ksum + ((size_t)(b * Lc + m)) * Dc + h * HDc);
                float4 acc = {0.f, 0.f, 0.f, 0.f};
                #pragma unroll
                for (int d = 0; d < 8; ++d) {
                    const float4 a = kt4[d];
                    const float4 c = ks4[d];
                    acc.x = fmaf(qr[d].x, a.x + c.x, acc.x);
                    acc.y = fmaf(qr[d].y, a.y + c.y, acc.y);
                    acc.z = fmaf(qr[d].z, a.z + c.z, acc.z);
                    acc.w = fmaf(qr[d].w, a.w + c.w, acc.w);
                }
                sc = (acc.x + acc.y + acc.z + acc.w) * scale;
            }
            sS[h][m] = sc;
        }
        __syncthreads();

        // ---- Softmax: one 64-lane wave per head ----
        const int hw = t >> 6;
        const int lane = t & 63;
        float x[4];
        #pragma unroll
        for (int j = 0; j < 4; ++j) x[j] = sS[hw][lane + j * 64];
        float mx = fmaxf(fmaxf(x[0], x[1]), fmaxf(x[2], x[3]));
        #pragma unroll
        for (int o = 32; o > 0; o >>= 1) mx = fmaxf(mx, __shfl_xor(mx, o, 64));
        float e[4], s = 0.f;
        #pragma unroll
        for (int j = 0; j < 4; ++j) { e[j] = __expf(x[j] - mx); s += e[j]; }
        #pragma unroll
        for (int o = 32; o > 0; o >>= 1) s += __shfl_xor(s, o, 64);
        const float inv = 1.0f / s;
        #pragma unroll
        for (int j = 0; j < 4; ++j) wT[lane + j * 64][hw] = e[j] * inv;
    } else {
        // Padded row: every score is NEG -> softmax is exactly uniform.
        const int h  = t & 3;
        const int m0 = t >> 2;
        #pragma unroll
        for (int j = 0; j < 4; ++j) wT[m0 + j * 64][h] = 1.0f / 256.0f;
    }
    __syncthreads();

    // ---- Phase B: out = sum_m w * (vsum + tV). thread t -> float4-col, m-group ----
    const int col = t & 31;        // float4 column 0..31 (component c = col*4)
    const int mg  = t >> 5;        // 0..7, m = mg, mg+8, ...
    const int hB  = col >> 3;      // head of this column
    const int mEnd = padded ? Lc : (l + 1);
    const float4* tV4 = (const float4*)(tV + ((size_t)(b * Lc + l)) * Lc * Dc);
    const float4* vs4 = (const float4*)(vsum + (size_t)b * Lc * Dc);

    float4 acc = {0.f, 0.f, 0.f, 0.f};
    for (int m = mg; m < mEnd; m += 8) {
        const float w = wT[m][hB];
        const float4 tv = tV4[(size_t)m * 32 + col];
        const float4 vv = vs4[(size_t)m * 32 + col];
        acc.x = fmaf(w, tv.x + vv.x, acc.x);
        acc.y = fmaf(w, tv.y + vv.y, acc.y);
        acc.z = fmaf(w, tv.z + vv.z, acc.z);
        acc.w = fmaf(w, tv.w + vv.w, acc.w);
    }
    pAcc[mg][col] = acc;
    __syncthreads();

    if (t < 32) {
        float4 s = pAcc[0][t];
        #pragma unroll
        for (int g = 1; g < 8; ++g) {
            const float4 p = pAcc[g][t];
            s.x += p.x; s.y += p.y; s.z += p.z; s.w += p.w;
        }
        *(float4*)&out[((size_t)(b * Lc + l)) * Dc + t * 4] = s;
    }
}

// ---------------------------------------------------------------------------
extern "C" void kernel_launch(void* const* d_in, const int* in_sizes, int n_in,
                              void* d_out, int out_size, void* d_ws, size_t ws_size,
                              hipStream_t stream)
{
    const float* queries = (const float*)d_in[0];
    const float* keys    = (const float*)d_in[1];
    const unsigned char* pmask = (const unsigned char*)d_in[2];
    const unsigned char* amask = (const unsigned char*)d_in[3];
    const float* pk = (const float*)d_in[4];
    const float* pv = (const float*)d_in[5];
    const float* tK = (const float*)d_in[6];
    const float* tV = (const float*)d_in[7];
    const float* Wq = (const float*)d_in[8];
    const float* bq = (const float*)d_in[9];
    const float* Wk = (const float*)d_in[10];
    const float* bk = (const float*)d_in[11];
    const float* Wv = (const float*)d_in[12];
    const float* bv = (const float*)d_in[13];
    float* out = (float*)d_out;

    // Workspace layout: qproj | ksum | vsum  (3 x 1 MB)
    float* qproj = (float*)d_ws;
    float* ksumW = qproj + (size_t)Bc * Lc * Dc;
    float* vsumW = ksumW + (size_t)Bc * Lc * Dc;

    proj_kernel<<<(Bc * Lc) / 8, 256, 0, stream>>>(
        queries, keys, pk, pv, Wq, bq, Wk, bk, Wv, bv, qproj, ksumW, vsumW);

    attn_kernel<<<Bc * Lc, 256, 0, stream>>>(
        qproj, ksumW, vsumW, tK, tV, pmask, amask, out);
}

// Round 2
// 521.362 us; speedup vs baseline: 1.0376x; 1.0376x over previous
//
#include <hip/hip_runtime.h>
#include <hip/hip_bf16.h>

// Problem constants (fixed by the reference): B=8, L=256, D=128, H=4, HD=32
constexpr int Bc = 8;
constexpr int Lc = 256;
constexpr int Dc = 128;
constexpr int Hc = 4;
constexpr int HDc = 32;
constexpr int NITEMS = Bc * Lc;   // 2048 (b,l) work items

// ---------------------------------------------------------------------------
// Kernel 1: fused projections
//   qout = queries @ Wq + bq
//   ksum = keys    @ Wk + bk + abs_pos_K
//   vsum = keys    @ Wv + bv + abs_pos_V
// Also zeroes the work-stealing counter for kernel 2 (re-poisoned to 0xAA by
// the harness before every timed launch).
// ---------------------------------------------------------------------------
__global__ __launch_bounds__(256)
void proj_kernel(const float* __restrict__ queries, const float* __restrict__ keys,
                 const float* __restrict__ pk, const float* __restrict__ pv,
                 const float* __restrict__ Wq, const float* __restrict__ bq,
                 const float* __restrict__ Wk, const float* __restrict__ bk,
                 const float* __restrict__ Wv, const float* __restrict__ bv,
                 float* __restrict__ qout, float* __restrict__ ksum,
                 float* __restrict__ vsum, int* __restrict__ counter)
{
    if (blockIdx.x == 0 && threadIdx.x == 0) *counter = 0;

    __shared__ float Aq[8][132];   // +4 pad: conflict-free, float4-aligned
    __shared__ float Ak[8][132];
    const int t = threadIdx.x;
    const int row0 = blockIdx.x * 8;

    {
        const int r = t >> 5;
        const int c4 = (t & 31) * 4;
        const float4 qv = *(const float4*)&queries[(size_t)(row0 + r) * Dc + c4];
        const float4 kv = *(const float4*)&keys[(size_t)(row0 + r) * Dc + c4];
        *(float4*)&Aq[r][c4] = qv;
        *(float4*)&Ak[r][c4] = kv;
    }
    __syncthreads();

    const int col = t & 127;
    const int rg  = t >> 7;      // 0..1 -> rows rg*4 .. rg*4+3
    float fq[4] = {0.f, 0.f, 0.f, 0.f};
    float fk[4] = {0.f, 0.f, 0.f, 0.f};
    float fv[4] = {0.f, 0.f, 0.f, 0.f};

    for (int k = 0; k < Dc; k += 4) {
        float4 a[4], c[4];
        #pragma unroll
        for (int r = 0; r < 4; ++r) {
            a[r] = *(const float4*)&Aq[rg * 4 + r][k];
            c[r] = *(const float4*)&Ak[rg * 4 + r][k];
        }
        #pragma unroll
        for (int kk = 0; kk < 4; ++kk) {
            const float wq = Wq[(size_t)(k + kk) * Dc + col];
            const float wk = Wk[(size_t)(k + kk) * Dc + col];
            const float wv = Wv[(size_t)(k + kk) * Dc + col];
            #pragma unroll
            for (int r = 0; r < 4; ++r) {
                const float av = (&a[r].x)[kk];
                const float cv = (&c[r].x)[kk];
                fq[r] = fmaf(av, wq, fq[r]);
                fk[r] = fmaf(cv, wk, fk[r]);
                fv[r] = fmaf(cv, wv, fv[r]);
            }
        }
    }

    const float bqv = bq[col], bkv = bk[col], bvv = bv[col];
    #pragma unroll
    for (int r = 0; r < 4; ++r) {
        const int row = row0 + rg * 4 + r;
        const size_t idx = (size_t)row * Dc + col;
        qout[idx] = fq[r] + bqv;
        ksum[idx] = fk[r] + bkv + pk[idx];
        vsum[idx] = fv[r] + bvv + pv[idx];
    }
}

// ---------------------------------------------------------------------------
// Kernel 2: fused time-aware attention with dynamic work stealing.
// 1024 blocks (4/CU) pull (b,l) items from an atomic counter, largest-first
// (l descending = LPT): avoids the static-mapping pathology where one CU gets
// 8 same-l blocks (2x mean traffic -> 2x runtime).
//   scores[h][m] = q . (ksum[b,m] + tK[b,l,m]) / sqrt(32), causal m <= l
//   padded rows: softmax of all-NEG row is exactly uniform 1/256 (skip tK)
//   out = sum_m w * (vsum[b,m] + tV[b,l,m])
// ---------------------------------------------------------------------------
__global__ __launch_bounds__(256)
void attn_kernel(const float* __restrict__ qproj, const float* __restrict__ ksum,
                 const float* __restrict__ vsum, const float* __restrict__ tK,
                 const float* __restrict__ tV,
                 const unsigned char* __restrict__ pmask,
                 const unsigned char* __restrict__ amask,
                 int* __restrict__ counter, float* __restrict__ out)
{
    __shared__ float  sS[Hc][Lc + 8];   // stride 264: <=2-way (free) on score store
    __shared__ float  wT[Lc][5];        // stride 5: conflict-free store + broadcast read
    __shared__ float4 pAcc[8][32];      // phase-B partials
    __shared__ int    sIdx;

    const int t = threadIdx.x;
    // Runtime bool-encoding detection: attn_mask[0][1] is True by construction.
    const int pmStride = (amask[1] != 0) ? 1 : 4;
    const float scale = 0.17677669529663687f;  // 1/sqrt(HD)

    for (;;) {
        if (t == 0) sIdx = atomicAdd(counter, 1);
        __syncthreads();                       // broadcast sIdx; fences prior-item LDS
        const int idx = sIdx;
        if (idx >= NITEMS) break;              // block-uniform

        const int l = 255 - (idx >> 3);        // largest causal extent first (LPT)
        const int b = idx & 7;
        const bool padded = pmask[(size_t)(b * Lc + l) * pmStride] != 0;

        if (!padded) {
            // ---- Phase A: scores. thread t -> head h = t&3, m = (t>>2)+j*64 ----
            const int h  = t & 3;
            const int m0 = t >> 2;
            const float4* q4 = (const float4*)(qproj + ((size_t)(b * Lc + l)) * Dc + h * HDc);
            float4 qr[8];
            #pragma unroll
            for (int i = 0; i < 8; ++i) qr[i] = q4[i];

            const float* tKbase = tK + ((size_t)(b * Lc + l)) * Lc * Dc;
            #pragma unroll
            for (int j = 0; j < 4; ++j) {
                const int m = m0 + j * 64;
                float sc = -3.0e38f;           // masked (future) positions
                if (m <= l) {
                    const float4* kt4 = (const float4*)(tKbase + (size_t)m * Dc + h * HDc);
                    const float4* ks4 = (const float4*)(ksum + ((size_t)(b * Lc + m)) * Dc + h * HDc);
                    float4 acc = {0.f, 0.f, 0.f, 0.f};
                    #pragma unroll
                    for (int d = 0; d < 8; ++d) {
                        const float4 a = kt4[d];
                        const float4 c = ks4[d];
                        acc.x = fmaf(qr[d].x, a.x + c.x, acc.x);
                        acc.y = fmaf(qr[d].y, a.y + c.y, acc.y);
                        acc.z = fmaf(qr[d].z, a.z + c.z, acc.z);
                        acc.w = fmaf(qr[d].w, a.w + c.w, acc.w);
                    }
                    sc = (acc.x + acc.y + acc.z + acc.w) * scale;
                }
                sS[h][m] = sc;
            }
            __syncthreads();

            // ---- Softmax: one 64-lane wave per head ----
            const int hw = t >> 6;
            const int lane = t & 63;
            float x[4];
            #pragma unroll
            for (int j = 0; j < 4; ++j) x[j] = sS[hw][lane + j * 64];
            float mx = fmaxf(fmaxf(x[0], x[1]), fmaxf(x[2], x[3]));
            #pragma unroll
            for (int o = 32; o > 0; o >>= 1) mx = fmaxf(mx, __shfl_xor(mx, o, 64));
            float e[4], s = 0.f;
            #pragma unroll
            for (int j = 0; j < 4; ++j) { e[j] = __expf(x[j] - mx); s += e[j]; }
            #pragma unroll
            for (int o = 32; o > 0; o >>= 1) s += __shfl_xor(s, o, 64);
            const float inv = 1.0f / s;
            #pragma unroll
            for (int j = 0; j < 4; ++j) wT[lane + j * 64][hw] = e[j] * inv;
        } else {
            // Padded row: every score is NEG -> softmax is exactly uniform.
            const int h  = t & 3;
            const int m0 = t >> 2;
            #pragma unroll
            for (int j = 0; j < 4; ++j) wT[m0 + j * 64][h] = 1.0f / 256.0f;
        }
        __syncthreads();

        // ---- Phase B: out = sum_m w * (vsum + tV) ----
        const int col = t & 31;        // float4 column 0..31
        const int mg  = t >> 5;        // 0..7
        const int hB  = col >> 3;      // head of this column
        const int mEnd = padded ? Lc : (l + 1);
        const float4* tV4 = (const float4*)(tV + ((size_t)(b * Lc + l)) * Lc * Dc);
        const float4* vs4 = (const float4*)(vsum + (size_t)b * Lc * Dc);

        float4 acc = {0.f, 0.f, 0.f, 0.f};
        #pragma unroll 2
        for (int m = mg; m < mEnd; m += 8) {
            const float w = wT[m][hB];
            const float4 tv = tV4[(size_t)m * 32 + col];
            const float4 vv = vs4[(size_t)m * 32 + col];
            acc.x = fmaf(w, tv.x + vv.x, acc.x);
            acc.y = fmaf(w, tv.y + vv.y, acc.y);
            acc.z = fmaf(w, tv.z + vv.z, acc.z);
            acc.w = fmaf(w, tv.w + vv.w, acc.w);
        }
        pAcc[mg][col] = acc;
        __syncthreads();

        if (t < 32) {
            float4 s = pAcc[0][t];
            #pragma unroll
            for (int g = 1; g < 8; ++g) {
                const float4 p = pAcc[g][t];
                s.x += p.x; s.y += p.y; s.z += p.z; s.w += p.w;
            }
            *(float4*)&out[((size_t)(b * Lc + l)) * Dc + t * 4] = s;
        }
        // loop back: next sIdx write by t0 happens after the pAcc barrier,
        // which every reader of this item's LDS has already passed.
    }
}

// ---------------------------------------------------------------------------
extern "C" void kernel_launch(void* const* d_in, const int* in_sizes, int n_in,
                              void* d_out, int out_size, void* d_ws, size_t ws_size,
                              hipStream_t stream)
{
    const float* queries = (const float*)d_in[0];
    const float* keys    = (const float*)d_in[1];
    const unsigned char* pmask = (const unsigned char*)d_in[2];
    const unsigned char* amask = (const unsigned char*)d_in[3];
    const float* pk = (const float*)d_in[4];
    const float* pv = (const float*)d_in[5];
    const float* tK = (const float*)d_in[6];
    const float* tV = (const float*)d_in[7];
    const float* Wq = (const float*)d_in[8];
    const float* bq = (const float*)d_in[9];
    const float* Wk = (const float*)d_in[10];
    const float* bk = (const float*)d_in[11];
    const float* Wv = (const float*)d_in[12];
    const float* bv = (const float*)d_in[13];
    float* out = (float*)d_out;

    // Workspace layout: qproj | ksum | vsum (3 x 1 MB) | counter
    float* qproj = (float*)d_ws;
    float* ksumW = qproj + (size_t)Bc * Lc * Dc;
    float* vsumW = ksumW + (size_t)Bc * Lc * Dc;
    int*   counter = (int*)(vsumW + (size_t)Bc * Lc * Dc);

    proj_kernel<<<(Bc * Lc) / 8, 256, 0, stream>>>(
        queries, keys, pk, pv, Wq, bq, Wk, bk, Wv, bv, qproj, ksumW, vsumW, counter);

    attn_kernel<<<1024, 256, 0, stream>>>(
        qproj, ksumW, vsumW, tK, tV, pmask, amask, counter, out);
}